// Round 17
// baseline (23.453 us; speedup 1.0000x reference)
//
#include <hip/hip_runtime.h>
#include <math.h>

typedef __attribute__((ext_vector_type(8))) _Float16 f16x8;
typedef __attribute__((ext_vector_type(4))) float f32x4;

#define TSTEPS 23
#define ROWS 128

// ws byte offsets
#define WSB_B1 0        // [64 n][168 k] f16 combined table *256 (21504 B)
#define WSB_W2 21504    // [64 n][72 k] f16 rw2 transposed (9216 B)
#define WSB_Z  30720    // [64][64] f32 RAW gate logit LUT (16384 B)

// ---- precompute: VERBATIM R16 ----
__global__ __launch_bounds__(512) void pre_all(
    const float* __restrict__ embed, const float* __restrict__ gw1,
    const float* __restrict__ gb1, const float* __restrict__ gw2,
    const float* __restrict__ gb2, const float* __restrict__ rw1,
    const float* __restrict__ rb1, const float* __restrict__ rw2,
    char* __restrict__ wsc)
{
    __shared__ float sE[66 * 64];
    __shared__ float sW[128 * 64];
    __shared__ float sV[64 * 33];
    __shared__ float sU[32];
    __shared__ float sG[65];
    __shared__ float sRb1[64];

    const int tid = threadIdx.x;
    const int blk = blockIdx.x;

    if (blk < 64) {
        {
            #pragma unroll
            for (int i = 0; i < 8; ++i) {
                const int e = tid + i * 512;
                const int s = e >> 6, k = e & 63;
                sE[k * 65 + s] = embed[s * 64 + k];
            }
            const float4* gs = (const float4*)gw1;
            float4* gd = (float4*)sW;
            for (int i = tid; i < 1024; i += 512) gd[i] = gs[i];
            if (tid < 32) { sG[tid] = gb1[tid]; sG[32 + tid] = gw2[tid]; }
            if (tid == 64) sG[64] = gb2[0];
        }
        __syncthreads();
        if (tid < 128) {
            const int s0 = (tid >> 3) * 4, j0 = (tid & 7) * 4;
            float acc[4][4];
            #pragma unroll
            for (int a = 0; a < 4; ++a)
                #pragma unroll
                for (int b = 0; b < 4; ++b) acc[a][b] = 0.f;
            #pragma unroll
            for (int k = 0; k < 64; ++k) {
                const float4 e4 = *(const float4*)&sE[k * 65 + s0];
                const float4 w4 = *(const float4*)&sW[(64 + k) * 32 + j0];
                acc[0][0] = fmaf(e4.x, w4.x, acc[0][0]); acc[0][1] = fmaf(e4.x, w4.y, acc[0][1]);
                acc[0][2] = fmaf(e4.x, w4.z, acc[0][2]); acc[0][3] = fmaf(e4.x, w4.w, acc[0][3]);
                acc[1][0] = fmaf(e4.y, w4.x, acc[1][0]); acc[1][1] = fmaf(e4.y, w4.y, acc[1][1]);
                acc[1][2] = fmaf(e4.y, w4.z, acc[1][2]); acc[1][3] = fmaf(e4.y, w4.w, acc[1][3]);
                acc[2][0] = fmaf(e4.z, w4.x, acc[2][0]); acc[2][1] = fmaf(e4.z, w4.y, acc[2][1]);
                acc[2][2] = fmaf(e4.z, w4.z, acc[2][2]); acc[2][3] = fmaf(e4.z, w4.w, acc[2][3]);
                acc[3][0] = fmaf(e4.w, w4.x, acc[3][0]); acc[3][1] = fmaf(e4.w, w4.y, acc[3][1]);
                acc[3][2] = fmaf(e4.w, w4.z, acc[3][2]); acc[3][3] = fmaf(e4.w, w4.w, acc[3][3]);
            }
            #pragma unroll
            for (int a = 0; a < 4; ++a)
                #pragma unroll
                for (int b = 0; b < 4; ++b)
                    sV[(s0 + a) * 33 + j0 + b] = acc[a][b];
        } else if (tid < 160) {
            const int j = tid - 128;
            float acc = 0.f;
            #pragma unroll
            for (int k = 0; k < 64; ++k)
                acc = fmaf(sE[k * 65 + blk], sW[k * 32 + j], acc);
            sU[j] = acc;
        }
        __syncthreads();
        if (tid < 64) {
            const int s = tid;
            float p0 = 0.f, p1 = 0.f, p2 = 0.f, p3 = 0.f;
            #pragma unroll
            for (int j = 0; j < 32; j += 4) {
                const float a0 = sU[j]     + sV[s * 33 + j]     + sG[j];
                const float a1 = sU[j + 1] + sV[s * 33 + j + 1] + sG[j + 1];
                const float a2 = sU[j + 2] + sV[s * 33 + j + 2] + sG[j + 2];
                const float a3 = sU[j + 3] + sV[s * 33 + j + 3] + sG[j + 3];
                if (a0 > 0.f) p0 = fmaf(a0, sG[32 + j],     p0);
                if (a1 > 0.f) p1 = fmaf(a1, sG[32 + j + 1], p1);
                if (a2 > 0.f) p2 = fmaf(a2, sG[32 + j + 2], p2);
                if (a3 > 0.f) p3 = fmaf(a3, sG[32 + j + 3], p3);
            }
            const float z = sG[64] + ((p0 + p1) + (p2 + p3));
            ((float*)(wsc + WSB_Z))[blk * 64 + s] = z;
        }
    } else if (blk < 81) {
        {
            const float4* es = (const float4*)embed;
            float4* ed = (float4*)sE;
            for (int i = tid; i < 1056; i += 512) ed[i] = es[i];
            const float4* rs = (const float4*)rw1;
            float4* rd = (float4*)sW;
            for (int i = tid; i < 2048; i += 512) rd[i] = rs[i];
            if (tid < 64) sRb1[tid] = rb1[tid];
        }
        __syncthreads();
        const int e = (blk - 64) * 512 + tid;
        if (e < 8320) {
            const int n = e & 63, k = e >> 6;
            const int trow = (k < 64) ? k : (k - 64);
            const int ofs = (k < 64) ? 64 : 0;
            float4 er[16];
            const float4* erp = (const float4*)(sE + trow * 64);
            #pragma unroll
            for (int q = 0; q < 16; ++q) er[q] = erp[q];
            float acc = (k < 64) ? 0.f : sRb1[n];
            #pragma unroll
            for (int m = 0; m < 64; ++m)
                acc = fmaf(((const float*)er)[m], sW[(ofs + m) * 64 + n], acc);
            acc *= (k < 64) ? (0.125f * 256.f) : 256.f;
            ((_Float16*)(wsc + WSB_B1))[n * 168 + k] = (_Float16)acc;
        }
    } else {
        _Float16* w2t = (_Float16*)(wsc + WSB_W2);
        for (int e = tid; e < 4096; e += 512) {
            const int n = e & 63, j = e >> 6;
            w2t[n * 72 + j] = (_Float16)rw2[j * 64 + n];
        }
        _Float16* b1 = (_Float16*)(wsc + WSB_B1);
        for (int e = tid; e < 2432; e += 512) {
            const int n = e / 38, k = 130 + (e - n * 38);
            b1[n * 168 + k] = (_Float16)0.f;
        }
    }
}

// ---- A-window builders (unchanged) ----
__device__ __forceinline__ f16x8 build_slot_win(const unsigned* s, const unsigned* hb, int ko)
{
    unsigned w0 = 0, w1 = 0, w2 = 0, w3 = 0;
    #pragma unroll
    for (int i = 0; i < 8; ++i) {
        const unsigned d = s[i] - (unsigned)ko;
        const unsigned val = (d < 8u) ? (hb[i] << ((d & 1u) * 16)) : 0u;
        const unsigned q = d >> 1;
        w0 |= (q == 0u) ? val : 0u;
        w1 |= (q == 1u) ? val : 0u;
        w2 |= (q == 2u) ? val : 0u;
        w3 |= (q == 3u) ? val : 0u;
    }
    union { unsigned u[4]; f16x8 v; } r;
    r.u[0] = w0; r.u[1] = w1; r.u[2] = w2; r.u[3] = w3;
    return r.v;
}

__device__ __forceinline__ f16x8 build_q_win(int kq, int ko)
{
    const unsigned d = (unsigned)(kq - ko);
    const unsigned val = (d < 8u) ? (0x3C00u << ((d & 1u) * 16)) : 0u;
    const unsigned q = d >> 1;
    union { unsigned u[4]; f16x8 v; } r;
    r.u[0] = (q == 0u) ? val : 0u;
    r.u[1] = (q == 1u) ? val : 0u;
    r.u[2] = (q == 2u) ? val : 0u;
    r.u[3] = (q == 3u) ? val : 0u;
    return r.v;
}

// LDS byte offsets (68096 B arena) — sOut f32[128][68] overlays [0, 34816)
#define L_Z    0
#define L_B1   16640
#define L_W2   38144
#define L_H    47360
#define L_ROW  65792
#define L_RB2  67840

__global__ __launch_bounds__(512) void sm_main(
    const int* __restrict__ seqs, const int* __restrict__ qtok,
    const float* __restrict__ rb2, const char* __restrict__ wsc,
    float* __restrict__ out)
{
    __shared__ __align__(16) char smem[68096];
    float*    sZ   = (float*)(smem + L_Z);
    _Float16* sB1  = (_Float16*)(smem + L_B1);
    _Float16* sW2  = (_Float16*)(smem + L_W2);
    _Float16* sH   = (_Float16*)(smem + L_H);
    uint4*    sRow = (uint4*)(smem + L_ROW);
    float*    sRb2 = (float*)(smem + L_RB2);

    const int tid = threadIdx.x;
    const int base = blockIdx.x * ROWS;

    unsigned pk[6];
    int qt = 0;
    if (tid < ROWS) {
        const int4* sq = (const int4*)(seqs + (size_t)(base + tid) * 24);
        #pragma unroll
        for (int i = 0; i < 6; ++i) {
            const int4 w4 = sq[i];
            pk[i] = (unsigned)w4.x | ((unsigned)w4.y << 8) |
                    ((unsigned)w4.z << 16) | ((unsigned)w4.w << 24);
        }
        qt = qtok[base + tid];
    }

    {
        const float* zsrc = (const float*)(wsc + WSB_Z);
        #pragma unroll
        for (int i = 0; i < 8; ++i) {
            const int e = tid + i * 512;
            sZ[(e >> 6) * 65 + (e & 63)] = zsrc[e];
        }
        if (tid < 64) sRb2[tid] = rb2[tid];
    }
    __syncthreads();

    if (tid < ROWS) {
        unsigned lo = pk[0], hi = pk[1];
        #pragma unroll
        for (int t = 8; t < TSTEPS; ++t) {
            const int c = (int)((pk[t >> 2] >> ((t & 3) * 8)) & 255u);
            const float* zr = sZ + c * 65;
            float b = zr[lo & 63]; int am = 0; float z;
            z = zr[(lo >> 8) & 63];  if (z > b) { b = z; am = 1; }
            z = zr[(lo >> 16) & 63]; if (z > b) { b = z; am = 2; }
            z = zr[lo >> 24];        if (z > b) { b = z; am = 3; }
            z = zr[hi & 63];         if (z > b) { b = z; am = 4; }
            z = zr[(hi >> 8) & 63];  if (z > b) { b = z; am = 5; }
            z = zr[(hi >> 16) & 63]; if (z > b) { b = z; am = 6; }
            z = zr[hi >> 24];        if (z > b) { b = z; am = 7; }
            const unsigned cb = (unsigned)c;
            if (am < 4) { const int sh = am * 8; lo = (lo & ~(255u << sh)) | (cb << sh); }
            else        { const int sh = am * 8 - 32; hi = (hi & ~(255u << sh)) | (cb << sh); }
        }
        int t_[8] = { (int)(lo & 63), (int)((lo >> 8) & 63), (int)((lo >> 16) & 63), (int)(lo >> 24),
                      (int)(hi & 63), (int)((hi >> 8) & 63), (int)((hi >> 16) & 63), (int)(hi >> 24) };
        int tot[8] = {1, 1, 1, 1, 1, 1, 1, 1};
        #pragma unroll
        for (int i = 0; i < 8; ++i)
            #pragma unroll
            for (int j = i + 1; j < 8; ++j) {
                const int eq = (t_[i] == t_[j]);
                tot[i] += eq; tot[j] += eq;
            }
        unsigned tp = 0;
        #pragma unroll
        for (int i = 0; i < 8; ++i) tp |= (unsigned)tot[i] << (4 * i);
        sRow[tid] = make_uint4(lo & 0x3F3F3F3Fu, hi & 0x3F3F3F3Fu, tp, (unsigned)qt);
    } else {
        const int t2 = tid - 128;
        const float4* b1s = (const float4*)(wsc + WSB_B1);
        float4* b1d = (float4*)sB1;
        for (int i = t2; i < 1344; i += 384) b1d[i] = b1s[i];
        const float4* w2s = (const float4*)(wsc + WSB_W2);
        float4* w2d = (float4*)sW2;
        for (int i = t2; i < 576; i += 384) w2d[i] = w2s[i];
    }
    __syncthreads();

    const int lane = tid & 63;
    const int w = tid >> 6;
    const int c16 = lane & 15, g = lane >> 4;
    const int arow = w * 16 + c16;

    unsigned sl[8], hb[8];
    int kq;
    {
        const uint4 ri = sRow[arow];
        sl[0] = ri.x & 63u; sl[1] = (ri.x >> 8) & 63u;
        sl[2] = (ri.x >> 16) & 63u; sl[3] = ri.x >> 24;
        sl[4] = ri.y & 63u; sl[5] = (ri.y >> 8) & 63u;
        sl[6] = (ri.y >> 16) & 63u; sl[7] = ri.y >> 24;
        #pragma unroll
        for (int i = 0; i < 8; ++i) {
            const unsigned tot = (ri.z >> (4 * i)) & 15u;
            union { _Float16 h; unsigned short b; } cv;
            cv.h = (_Float16)(float)tot;
            hb[i] = (unsigned)cv.b;
        }
        kq = 64 + (int)ri.w;
    }

    f32x4 a0 = {0.f, 0.f, 0.f, 0.f}, a1 = a0, a2 = a0, a3 = a0;
    #pragma unroll
    for (int ks = 0; ks < 5; ++ks) {
        const int ko = ks * 32 + g * 8;
        const f16x8 af = (ks < 2) ? build_slot_win(sl, hb, ko) : build_q_win(kq, ko);
        const f16x8 b0 = *(const f16x8*)&sB1[(c16) * 168 + ko];
        const f16x8 b1 = *(const f16x8*)&sB1[(16 + c16) * 168 + ko];
        const f16x8 b2 = *(const f16x8*)&sB1[(32 + c16) * 168 + ko];
        const f16x8 b3 = *(const f16x8*)&sB1[(48 + c16) * 168 + ko];
        a0 = __builtin_amdgcn_mfma_f32_16x16x32_f16(af, b0, a0, 0, 0, 0);
        a1 = __builtin_amdgcn_mfma_f32_16x16x32_f16(af, b1, a1, 0, 0, 0);
        a2 = __builtin_amdgcn_mfma_f32_16x16x32_f16(af, b2, a2, 0, 0, 0);
        a3 = __builtin_amdgcn_mfma_f32_16x16x32_f16(af, b3, a3, 0, 0, 0);
    }
    {
        const int rbase = w * 16 + g * 4;
        #pragma unroll
        for (int j = 0; j < 4; ++j) {
            _Float16* hr = sH + (rbase + j) * 72;
            const float v0 = a0[j], v1 = a1[j], v2 = a2[j], v3 = a3[j];
            hr[c16]      = (_Float16)(v0 > 0.f ? v0 : 0.f);
            hr[16 + c16] = (_Float16)(v1 > 0.f ? v1 : 0.f);
            hr[32 + c16] = (_Float16)(v2 > 0.f ? v2 : 0.f);
            hr[48 + c16] = (_Float16)(v3 > 0.f ? v3 : 0.f);
        }
    }
    __syncthreads();

    f32x4 d0 = {0.f, 0.f, 0.f, 0.f}, d1 = d0, d2 = d0, d3 = d0;
    #pragma unroll
    for (int ks = 0; ks < 2; ++ks) {
        const int ko = ks * 32 + g * 8;
        const f16x8 af = *(const f16x8*)&sH[arow * 72 + ko];
        const f16x8 b0 = *(const f16x8*)&sW2[(c16) * 72 + ko];
        const f16x8 b1 = *(const f16x8*)&sW2[(16 + c16) * 72 + ko];
        const f16x8 b2 = *(const f16x8*)&sW2[(32 + c16) * 72 + ko];
        const f16x8 b3 = *(const f16x8*)&sW2[(48 + c16) * 72 + ko];
        d0 = __builtin_amdgcn_mfma_f32_16x16x32_f16(af, b0, d0, 0, 0, 0);
        d1 = __builtin_amdgcn_mfma_f32_16x16x32_f16(af, b1, d1, 0, 0, 0);
        d2 = __builtin_amdgcn_mfma_f32_16x16x32_f16(af, b2, d2, 0, 0, 0);
        d3 = __builtin_amdgcn_mfma_f32_16x16x32_f16(af, b3, d3, 0, 0, 0);
    }
    float* sOut = (float*)(void*)smem;
    {
        const int rbase = w * 16 + g * 4;
        #pragma unroll
        for (int j = 0; j < 4; ++j) {
            float* orow = sOut + (rbase + j) * 68;
            orow[c16]      = d0[j] * (1.f / 256.f) + sRb2[c16];
            orow[16 + c16] = d1[j] * (1.f / 256.f) + sRb2[16 + c16];
            orow[32 + c16] = d2[j] * (1.f / 256.f) + sRb2[32 + c16];
            orow[48 + c16] = d3[j] * (1.f / 256.f) + sRb2[48 + c16];
        }
    }
    __syncthreads();

    #pragma unroll
    for (int r2 = 0; r2 < 4; ++r2) {
        const int idx = r2 * 512 + tid;
        const int row = idx >> 4, c4 = idx & 15;
        *(float4*)(out + (size_t)(base + row) * 64 + c4 * 4) =
            *(const float4*)&sOut[row * 68 + c4 * 4];
    }
}

extern "C" void kernel_launch(void* const* d_in, const int* in_sizes, int n_in,
                              void* d_out, int out_size, void* d_ws, size_t ws_size,
                              hipStream_t stream)
{
    const int* seqs    = (const int*)d_in[0];
    const int* qtok    = (const int*)d_in[1];
    const float* embed = (const float*)d_in[2];
    const float* gw1   = (const float*)d_in[3];
    const float* gb1   = (const float*)d_in[4];
    const float* gw2   = (const float*)d_in[5];
    const float* gb2   = (const float*)d_in[6];
    const float* rw1   = (const float*)d_in[7];
    const float* rb1   = (const float*)d_in[8];
    const float* rw2   = (const float*)d_in[9];
    const float* rb2   = (const float*)d_in[10];
    char* wsc  = (char*)d_ws;
    float* out = (float*)d_out;
    const int B = in_sizes[1];

    // CALIBRATION: pre_all launched twice (idempotent — identical bytes).
    // marginal(second pre_all) = P + boundary, measured in non-first position.
    pre_all<<<82, 512, 0, stream>>>(embed, gw1, gb1, gw2, gb2, rw1, rb1, rw2, wsc);
    pre_all<<<82, 512, 0, stream>>>(embed, gw1, gb1, gw2, gb2, rw1, rb1, rw2, wsc);
    sm_main<<<B / ROWS, 512, 0, stream>>>(seqs, qtok, rb2, wsc, out);
}

// Round 18
// 18.814 us; speedup vs baseline: 1.2465x; 1.2465x over previous
//
#include <hip/hip_runtime.h>
#include <math.h>

typedef __attribute__((ext_vector_type(8))) _Float16 f16x8;
typedef __attribute__((ext_vector_type(4))) float f32x4;

#define TSTEPS 23
#define ROWS 128

// ws byte offsets
#define WSB_B1 0        // [64 n][168 k] f16 combined table *256 (21504 B)
#define WSB_W2 21504    // [64 n][72 k] f16 rw2 transposed (9216 B)
#define WSB_Z  30720    // [64][64] f32 RAW gate logit LUT (16384 B)

// ---- precompute: VERBATIM R16 (best measured: 19.1 us) ----
__global__ __launch_bounds__(512) void pre_all(
    const float* __restrict__ embed, const float* __restrict__ gw1,
    const float* __restrict__ gb1, const float* __restrict__ gw2,
    const float* __restrict__ gb2, const float* __restrict__ rw1,
    const float* __restrict__ rb1, const float* __restrict__ rw2,
    char* __restrict__ wsc)
{
    __shared__ float sE[66 * 64];
    __shared__ float sW[128 * 64];
    __shared__ float sV[64 * 33];
    __shared__ float sU[32];
    __shared__ float sG[65];
    __shared__ float sRb1[64];

    const int tid = threadIdx.x;
    const int blk = blockIdx.x;

    if (blk < 64) {
        {
            #pragma unroll
            for (int i = 0; i < 8; ++i) {
                const int e = tid + i * 512;
                const int s = e >> 6, k = e & 63;
                sE[k * 65 + s] = embed[s * 64 + k];
            }
            const float4* gs = (const float4*)gw1;
            float4* gd = (float4*)sW;
            for (int i = tid; i < 1024; i += 512) gd[i] = gs[i];
            if (tid < 32) { sG[tid] = gb1[tid]; sG[32 + tid] = gw2[tid]; }
            if (tid == 64) sG[64] = gb2[0];
        }
        __syncthreads();
        if (tid < 128) {
            const int s0 = (tid >> 3) * 4, j0 = (tid & 7) * 4;
            float acc[4][4];
            #pragma unroll
            for (int a = 0; a < 4; ++a)
                #pragma unroll
                for (int b = 0; b < 4; ++b) acc[a][b] = 0.f;
            #pragma unroll
            for (int k = 0; k < 64; ++k) {
                const float4 e4 = *(const float4*)&sE[k * 65 + s0];
                const float4 w4 = *(const float4*)&sW[(64 + k) * 32 + j0];
                acc[0][0] = fmaf(e4.x, w4.x, acc[0][0]); acc[0][1] = fmaf(e4.x, w4.y, acc[0][1]);
                acc[0][2] = fmaf(e4.x, w4.z, acc[0][2]); acc[0][3] = fmaf(e4.x, w4.w, acc[0][3]);
                acc[1][0] = fmaf(e4.y, w4.x, acc[1][0]); acc[1][1] = fmaf(e4.y, w4.y, acc[1][1]);
                acc[1][2] = fmaf(e4.y, w4.z, acc[1][2]); acc[1][3] = fmaf(e4.y, w4.w, acc[1][3]);
                acc[2][0] = fmaf(e4.z, w4.x, acc[2][0]); acc[2][1] = fmaf(e4.z, w4.y, acc[2][1]);
                acc[2][2] = fmaf(e4.z, w4.z, acc[2][2]); acc[2][3] = fmaf(e4.z, w4.w, acc[2][3]);
                acc[3][0] = fmaf(e4.w, w4.x, acc[3][0]); acc[3][1] = fmaf(e4.w, w4.y, acc[3][1]);
                acc[3][2] = fmaf(e4.w, w4.z, acc[3][2]); acc[3][3] = fmaf(e4.w, w4.w, acc[3][3]);
            }
            #pragma unroll
            for (int a = 0; a < 4; ++a)
                #pragma unroll
                for (int b = 0; b < 4; ++b)
                    sV[(s0 + a) * 33 + j0 + b] = acc[a][b];
        } else if (tid < 160) {
            const int j = tid - 128;
            float acc = 0.f;
            #pragma unroll
            for (int k = 0; k < 64; ++k)
                acc = fmaf(sE[k * 65 + blk], sW[k * 32 + j], acc);
            sU[j] = acc;
        }
        __syncthreads();
        if (tid < 64) {
            const int s = tid;
            float p0 = 0.f, p1 = 0.f, p2 = 0.f, p3 = 0.f;
            #pragma unroll
            for (int j = 0; j < 32; j += 4) {
                const float a0 = sU[j]     + sV[s * 33 + j]     + sG[j];
                const float a1 = sU[j + 1] + sV[s * 33 + j + 1] + sG[j + 1];
                const float a2 = sU[j + 2] + sV[s * 33 + j + 2] + sG[j + 2];
                const float a3 = sU[j + 3] + sV[s * 33 + j + 3] + sG[j + 3];
                if (a0 > 0.f) p0 = fmaf(a0, sG[32 + j],     p0);
                if (a1 > 0.f) p1 = fmaf(a1, sG[32 + j + 1], p1);
                if (a2 > 0.f) p2 = fmaf(a2, sG[32 + j + 2], p2);
                if (a3 > 0.f) p3 = fmaf(a3, sG[32 + j + 3], p3);
            }
            const float z = sG[64] + ((p0 + p1) + (p2 + p3));
            ((float*)(wsc + WSB_Z))[blk * 64 + s] = z;
        }
    } else if (blk < 81) {
        {
            const float4* es = (const float4*)embed;
            float4* ed = (float4*)sE;
            for (int i = tid; i < 1056; i += 512) ed[i] = es[i];
            const float4* rs = (const float4*)rw1;
            float4* rd = (float4*)sW;
            for (int i = tid; i < 2048; i += 512) rd[i] = rs[i];
            if (tid < 64) sRb1[tid] = rb1[tid];
        }
        __syncthreads();
        const int e = (blk - 64) * 512 + tid;
        if (e < 8320) {
            const int n = e & 63, k = e >> 6;
            const int trow = (k < 64) ? k : (k - 64);
            const int ofs = (k < 64) ? 64 : 0;
            float4 er[16];
            const float4* erp = (const float4*)(sE + trow * 64);
            #pragma unroll
            for (int q = 0; q < 16; ++q) er[q] = erp[q];
            float acc = (k < 64) ? 0.f : sRb1[n];
            #pragma unroll
            for (int m = 0; m < 64; ++m)
                acc = fmaf(((const float*)er)[m], sW[(ofs + m) * 64 + n], acc);
            acc *= (k < 64) ? (0.125f * 256.f) : 256.f;
            ((_Float16*)(wsc + WSB_B1))[n * 168 + k] = (_Float16)acc;
        }
    } else {
        _Float16* w2t = (_Float16*)(wsc + WSB_W2);
        for (int e = tid; e < 4096; e += 512) {
            const int n = e & 63, j = e >> 6;
            w2t[n * 72 + j] = (_Float16)rw2[j * 64 + n];
        }
        _Float16* b1 = (_Float16*)(wsc + WSB_B1);
        for (int e = tid; e < 2432; e += 512) {
            const int n = e / 38, k = 130 + (e - n * 38);
            b1[n * 168 + k] = (_Float16)0.f;
        }
    }
}

// ---- A-window builders (unchanged) ----
__device__ __forceinline__ f16x8 build_slot_win(const unsigned* s, const unsigned* hb, int ko)
{
    unsigned w0 = 0, w1 = 0, w2 = 0, w3 = 0;
    #pragma unroll
    for (int i = 0; i < 8; ++i) {
        const unsigned d = s[i] - (unsigned)ko;
        const unsigned val = (d < 8u) ? (hb[i] << ((d & 1u) * 16)) : 0u;
        const unsigned q = d >> 1;
        w0 |= (q == 0u) ? val : 0u;
        w1 |= (q == 1u) ? val : 0u;
        w2 |= (q == 2u) ? val : 0u;
        w3 |= (q == 3u) ? val : 0u;
    }
    union { unsigned u[4]; f16x8 v; } r;
    r.u[0] = w0; r.u[1] = w1; r.u[2] = w2; r.u[3] = w3;
    return r.v;
}

__device__ __forceinline__ f16x8 build_q_win(int kq, int ko)
{
    const unsigned d = (unsigned)(kq - ko);
    const unsigned val = (d < 8u) ? (0x3C00u << ((d & 1u) * 16)) : 0u;
    const unsigned q = d >> 1;
    union { unsigned u[4]; f16x8 v; } r;
    r.u[0] = (q == 0u) ? val : 0u;
    r.u[1] = (q == 1u) ? val : 0u;
    r.u[2] = (q == 2u) ? val : 0u;
    r.u[3] = (q == 3u) ? val : 0u;
    return r.v;
}

// LDS byte offsets (68096 B arena) — sOut f32[128][68] overlays [0, 34816)
#define L_Z    0
#define L_B1   16640
#define L_W2   38144
#define L_H    47360
#define L_ROW  65792
#define L_RB2  67840

__global__ __launch_bounds__(512) void sm_main(
    const int* __restrict__ seqs, const int* __restrict__ qtok,
    const float* __restrict__ rb2, const char* __restrict__ wsc,
    float* __restrict__ out)
{
    __shared__ __align__(16) char smem[68096];
    float*    sZ   = (float*)(smem + L_Z);
    _Float16* sB1  = (_Float16*)(smem + L_B1);
    _Float16* sW2  = (_Float16*)(smem + L_W2);
    _Float16* sH   = (_Float16*)(smem + L_H);
    uint4*    sRow = (uint4*)(smem + L_ROW);
    float*    sRb2 = (float*)(smem + L_RB2);

    const int tid = threadIdx.x;
    const int base = blockIdx.x * ROWS;

    unsigned pk[6];
    int qt = 0;
    if (tid < ROWS) {
        const int4* sq = (const int4*)(seqs + (size_t)(base + tid) * 24);
        #pragma unroll
        for (int i = 0; i < 6; ++i) {
            const int4 w4 = sq[i];
            pk[i] = (unsigned)w4.x | ((unsigned)w4.y << 8) |
                    ((unsigned)w4.z << 16) | ((unsigned)w4.w << 24);
        }
        qt = qtok[base + tid];
    }

    {
        const float* zsrc = (const float*)(wsc + WSB_Z);
        #pragma unroll
        for (int i = 0; i < 8; ++i) {
            const int e = tid + i * 512;
            sZ[(e >> 6) * 65 + (e & 63)] = zsrc[e];
        }
        if (tid < 64) sRb2[tid] = rb2[tid];
    }
    __syncthreads();

    if (tid < ROWS) {
        unsigned lo = pk[0], hi = pk[1];
        #pragma unroll
        for (int t = 8; t < TSTEPS; ++t) {
            const int c = (int)((pk[t >> 2] >> ((t & 3) * 8)) & 255u);
            const float* zr = sZ + c * 65;
            float b = zr[lo & 63]; int am = 0; float z;
            z = zr[(lo >> 8) & 63];  if (z > b) { b = z; am = 1; }
            z = zr[(lo >> 16) & 63]; if (z > b) { b = z; am = 2; }
            z = zr[lo >> 24];        if (z > b) { b = z; am = 3; }
            z = zr[hi & 63];         if (z > b) { b = z; am = 4; }
            z = zr[(hi >> 8) & 63];  if (z > b) { b = z; am = 5; }
            z = zr[(hi >> 16) & 63]; if (z > b) { b = z; am = 6; }
            z = zr[hi >> 24];        if (z > b) { b = z; am = 7; }
            const unsigned cb = (unsigned)c;
            if (am < 4) { const int sh = am * 8; lo = (lo & ~(255u << sh)) | (cb << sh); }
            else        { const int sh = am * 8 - 32; hi = (hi & ~(255u << sh)) | (cb << sh); }
        }
        int t_[8] = { (int)(lo & 63), (int)((lo >> 8) & 63), (int)((lo >> 16) & 63), (int)(lo >> 24),
                      (int)(hi & 63), (int)((hi >> 8) & 63), (int)((hi >> 16) & 63), (int)(hi >> 24) };
        int tot[8] = {1, 1, 1, 1, 1, 1, 1, 1};
        #pragma unroll
        for (int i = 0; i < 8; ++i)
            #pragma unroll
            for (int j = i + 1; j < 8; ++j) {
                const int eq = (t_[i] == t_[j]);
                tot[i] += eq; tot[j] += eq;
            }
        unsigned tp = 0;
        #pragma unroll
        for (int i = 0; i < 8; ++i) tp |= (unsigned)tot[i] << (4 * i);
        sRow[tid] = make_uint4(lo & 0x3F3F3F3Fu, hi & 0x3F3F3F3Fu, tp, (unsigned)qt);
    } else {
        const int t2 = tid - 128;
        const float4* b1s = (const float4*)(wsc + WSB_B1);
        float4* b1d = (float4*)sB1;
        for (int i = t2; i < 1344; i += 384) b1d[i] = b1s[i];
        const float4* w2s = (const float4*)(wsc + WSB_W2);
        float4* w2d = (float4*)sW2;
        for (int i = t2; i < 576; i += 384) w2d[i] = w2s[i];
    }
    __syncthreads();

    const int lane = tid & 63;
    const int w = tid >> 6;
    const int c16 = lane & 15, g = lane >> 4;
    const int arow = w * 16 + c16;

    unsigned sl[8], hb[8];
    int kq;
    {
        const uint4 ri = sRow[arow];
        sl[0] = ri.x & 63u; sl[1] = (ri.x >> 8) & 63u;
        sl[2] = (ri.x >> 16) & 63u; sl[3] = ri.x >> 24;
        sl[4] = ri.y & 63u; sl[5] = (ri.y >> 8) & 63u;
        sl[6] = (ri.y >> 16) & 63u; sl[7] = ri.y >> 24;
        #pragma unroll
        for (int i = 0; i < 8; ++i) {
            const unsigned tot = (ri.z >> (4 * i)) & 15u;
            union { _Float16 h; unsigned short b; } cv;
            cv.h = (_Float16)(float)tot;
            hb[i] = (unsigned)cv.b;
        }
        kq = 64 + (int)ri.w;
    }

    f32x4 a0 = {0.f, 0.f, 0.f, 0.f}, a1 = a0, a2 = a0, a3 = a0;
    #pragma unroll
    for (int ks = 0; ks < 5; ++ks) {
        const int ko = ks * 32 + g * 8;
        const f16x8 af = (ks < 2) ? build_slot_win(sl, hb, ko) : build_q_win(kq, ko);
        const f16x8 b0 = *(const f16x8*)&sB1[(c16) * 168 + ko];
        const f16x8 b1 = *(const f16x8*)&sB1[(16 + c16) * 168 + ko];
        const f16x8 b2 = *(const f16x8*)&sB1[(32 + c16) * 168 + ko];
        const f16x8 b3 = *(const f16x8*)&sB1[(48 + c16) * 168 + ko];
        a0 = __builtin_amdgcn_mfma_f32_16x16x32_f16(af, b0, a0, 0, 0, 0);
        a1 = __builtin_amdgcn_mfma_f32_16x16x32_f16(af, b1, a1, 0, 0, 0);
        a2 = __builtin_amdgcn_mfma_f32_16x16x32_f16(af, b2, a2, 0, 0, 0);
        a3 = __builtin_amdgcn_mfma_f32_16x16x32_f16(af, b3, a3, 0, 0, 0);
    }
    {
        const int rbase = w * 16 + g * 4;
        #pragma unroll
        for (int j = 0; j < 4; ++j) {
            _Float16* hr = sH + (rbase + j) * 72;
            const float v0 = a0[j], v1 = a1[j], v2 = a2[j], v3 = a3[j];
            hr[c16]      = (_Float16)(v0 > 0.f ? v0 : 0.f);
            hr[16 + c16] = (_Float16)(v1 > 0.f ? v1 : 0.f);
            hr[32 + c16] = (_Float16)(v2 > 0.f ? v2 : 0.f);
            hr[48 + c16] = (_Float16)(v3 > 0.f ? v3 : 0.f);
        }
    }
    __syncthreads();

    f32x4 d0 = {0.f, 0.f, 0.f, 0.f}, d1 = d0, d2 = d0, d3 = d0;
    #pragma unroll
    for (int ks = 0; ks < 2; ++ks) {
        const int ko = ks * 32 + g * 8;
        const f16x8 af = *(const f16x8*)&sH[arow * 72 + ko];
        const f16x8 b0 = *(const f16x8*)&sW2[(c16) * 72 + ko];
        const f16x8 b1 = *(const f16x8*)&sW2[(16 + c16) * 72 + ko];
        const f16x8 b2 = *(const f16x8*)&sW2[(32 + c16) * 72 + ko];
        const f16x8 b3 = *(const f16x8*)&sW2[(48 + c16) * 72 + ko];
        d0 = __builtin_amdgcn_mfma_f32_16x16x32_f16(af, b0, d0, 0, 0, 0);
        d1 = __builtin_amdgcn_mfma_f32_16x16x32_f16(af, b1, d1, 0, 0, 0);
        d2 = __builtin_amdgcn_mfma_f32_16x16x32_f16(af, b2, d2, 0, 0, 0);
        d3 = __builtin_amdgcn_mfma_f32_16x16x32_f16(af, b3, d3, 0, 0, 0);
    }
    float* sOut = (float*)(void*)smem;
    {
        const int rbase = w * 16 + g * 4;
        #pragma unroll
        for (int j = 0; j < 4; ++j) {
            float* orow = sOut + (rbase + j) * 68;
            orow[c16]      = d0[j] * (1.f / 256.f) + sRb2[c16];
            orow[16 + c16] = d1[j] * (1.f / 256.f) + sRb2[16 + c16];
            orow[32 + c16] = d2[j] * (1.f / 256.f) + sRb2[32 + c16];
            orow[48 + c16] = d3[j] * (1.f / 256.f) + sRb2[48 + c16];
        }
    }
    __syncthreads();

    #pragma unroll
    for (int r2 = 0; r2 < 4; ++r2) {
        const int idx = r2 * 512 + tid;
        const int row = idx >> 4, c4 = idx & 15;
        *(float4*)(out + (size_t)(base + row) * 64 + c4 * 4) =
            *(const float4*)&sOut[row * 68 + c4 * 4];
    }
}

extern "C" void kernel_launch(void* const* d_in, const int* in_sizes, int n_in,
                              void* d_out, int out_size, void* d_ws, size_t ws_size,
                              hipStream_t stream)
{
    const int* seqs    = (const int*)d_in[0];
    const int* qtok    = (const int*)d_in[1];
    const float* embed = (const float*)d_in[2];
    const float* gw1   = (const float*)d_in[3];
    const float* gb1   = (const float*)d_in[4];
    const float* gw2   = (const float*)d_in[5];
    const float* gb2   = (const float*)d_in[6];
    const float* rw1   = (const float*)d_in[7];
    const float* rb1   = (const float*)d_in[8];
    const float* rw2   = (const float*)d_in[9];
    const float* rb2   = (const float*)d_in[10];
    char* wsc  = (char*)d_ws;
    float* out = (float*)d_out;
    const int B = in_sizes[1];

    pre_all<<<82, 512, 0, stream>>>(embed, gw1, gb1, gw2, gb2, rw1, rb1, rw2, wsc);
    sm_main<<<B / ROWS, 512, 0, stream>>>(seqs, qtok, rb2, wsc, out);
}